// Round 15
// baseline (170.924 us; speedup 1.0000x reference)
//
#include <hip/hip_runtime.h>
#include <cstdint>

typedef _Float16 f16;
typedef _Float16 f16x2 __attribute__((ext_vector_type(2)));
typedef _Float16 f16x4 __attribute__((ext_vector_type(4)));
typedef _Float16 f16x8 __attribute__((ext_vector_type(8)));
typedef float f32x4 __attribute__((ext_vector_type(4)));
typedef float f32x16 __attribute__((ext_vector_type(16)));

#define MFMA16(a, b, c) __builtin_amdgcn_mfma_f32_16x16x32_f16(a, b, c, 0, 0, 0)
#define MFMA32(a, b, c) __builtin_amdgcn_mfma_f32_32x32x16_f16(a, b, c, 0, 0, 0)
#define QSCALE 0.1803368801111243f  /* 0.125 * log2(e): scores land in log2 domain */

// direct global->LDS 16B async copy (m97 pattern)
__device__ __forceinline__ void gload_lds16(const void* g, void* l) {
    __builtin_amdgcn_global_load_lds((__attribute__((address_space(1))) void*)(g),
                                     (__attribute__((address_space(3))) void*)(l),
                                     16, 0, 0);
}

__device__ __forceinline__ unsigned pack2(float x, float y) {
    f16x2 t = {(f16)x, (f16)y};     // RNE casts + pack
    return __builtin_bit_cast(unsigned, t);
}

// Problem constants: S=2048, B=2, D=1024, H=16, DK=64
// ws layout (bytes):
//  xh   @ 0         : 4096x1024 f16 = 8 MB       (dead after gemm_qkv)
//  wqh  @ 8388608   : 3072x1024 f16 = 6 MB
//  woh  @ 14680064  : 1024x1024 f16 = 2 MB
//  qh   @ 16777216  : [32][2048][64] f16 = 8 MB  (PRE-SCALED by 0.125*log2e)
//  kh   @ 25165824  : [32][2048][64] f16 = 8 MB
//  vt   @ 33554432  : [32][64][2048] f16 = 8 MB  (V transposed, written by gemm_qkv)
//  ah   @ 41943040  : [4096][1024] f16 = 8 MB

// Single fused cast: outputs are contiguous in ws (xh | wqh | woh).
__global__ void cast_all(const float* __restrict__ x, const float* __restrict__ wqv,
                         const float* __restrict__ wo, f16* __restrict__ out) {
    int i = blockIdx.x * blockDim.x + threadIdx.x;  // 0..2097151 float4s
    const float* src; int li;
    if (i < 1048576)      { src = x;   li = i; }
    else if (i < 1835008) { src = wqv; li = i - 1048576; }
    else                  { src = wo;  li = i - 1835008; }
    float4 v = reinterpret_cast<const float4*>(src)[li];
    f16x4 o = {(f16)v.x, (f16)v.y, (f16)v.z, (f16)v.w};
    reinterpret_cast<f16x4*>(out)[i] = o;
}

// ---------------- QKV GEMM: C[4096x3072] = X[4096x1024] * Wqkv^T ----------------
// R19 structure kept (best): R7 ring-3 BK=32 + XCD-aware 2D-chunked remap.
__global__ __launch_bounds__(256, 3) void gemm_qkv(
    const f16* __restrict__ A, const f16* __restrict__ B,
    f16* __restrict__ outq, f16* __restrict__ outk, f16* __restrict__ outvt)
{
    __shared__ f16 As[3][128 * 32];
    __shared__ f16 Bs[3][128 * 32];
    const int tid = threadIdx.x;
    const int lane = tid & 63;
    const int wave = tid >> 6;
    const int wm = wave >> 1, wn = wave & 1;

    // XCD-aware 2D-chunked remap: HW linear id -> (bxx, byy) region per XCD
    const int wlin = blockIdx.x + 24 * blockIdx.y;
    const int xcd = wlin & 7;
    const int ii = wlin >> 3;                    // 0..95 within XCD
    const int bxx = 12 * (xcd & 1) + (ii % 12);  // 0..23
    const int byy = 8 * (xcd >> 1) + (ii / 12);  // 0..31

    const int bm = byy * 128, bn = bxx * 128;
    const int fr = lane & 15, fq = lane >> 4;

    const int srow = tid >> 2;                                    // 0..63
    const int su = (tid & 3) ^ (srow & 3) ^ ((srow >> 2) & 3);    // swizzled src 16B-unit
    const int uoff = (fq ^ (fr & 3) ^ ((fr >> 2) & 3)) * 8;       // lane-const read offset

    f32x4 acc[4][4] = {};

    auto stg = [&](int tt, int buf) {
        const int k0 = tt * 32;
        gload_lds16(&A[(bm + srow) * 1024 + k0 + su * 8],      &As[buf][tid * 8]);
        gload_lds16(&A[(bm + 64 + srow) * 1024 + k0 + su * 8], &As[buf][2048 + tid * 8]);
        gload_lds16(&B[(bn + srow) * 1024 + k0 + su * 8],      &Bs[buf][tid * 8]);
        gload_lds16(&B[(bn + 64 + srow) * 1024 + k0 + su * 8], &Bs[buf][2048 + tid * 8]);
    };

    auto step = [&](int t, int buf) {
        const int b2 = (buf + 2 >= 3) ? (buf - 1) : (buf + 2);
        if (t < 30) stg(t + 2, b2);
        f16x8 af[4], bf[4];
#pragma unroll
        for (int mt = 0; mt < 4; ++mt)
            af[mt] = *(const f16x8*)&As[buf][(wm * 64 + mt * 16 + fr) * 32 + uoff];
#pragma unroll
        for (int nt = 0; nt < 4; ++nt)
            bf[nt] = *(const f16x8*)&Bs[buf][(wn * 64 + nt * 16 + fr) * 32 + uoff];
        __builtin_amdgcn_s_setprio(1);
#pragma unroll
        for (int mt = 0; mt < 4; ++mt)
#pragma unroll
            for (int nt = 0; nt < 4; ++nt)
                acc[mt][nt] = MFMA16(af[mt], bf[nt], acc[mt][nt]);
        __builtin_amdgcn_s_setprio(0);
        if (t < 30) { asm volatile("s_waitcnt vmcnt(4)" ::: "memory"); }
        else        { asm volatile("s_waitcnt vmcnt(0)" ::: "memory"); }
        __builtin_amdgcn_s_barrier();
        __builtin_amdgcn_sched_barrier(0);
    };

    stg(0, 0);
    stg(1, 1);
    asm volatile("s_waitcnt vmcnt(4)" ::: "memory");
    __builtin_amdgcn_s_barrier();
    __builtin_amdgcn_sched_barrier(0);
#pragma unroll 1
    for (int tb = 0; tb < 30; tb += 3) {
        step(tb, 0);
        step(tb + 1, 1);
        step(tb + 2, 2);
    }
    step(30, 0);
    step(31, 1);

    const int x = bxx;
    if (x < 16) {
        // Q (x<8) or K block: uniform target, row-layout [bh][s][64]
        f16* base = (x < 8) ? outq : outk;
        const float scale = (x < 8) ? QSCALE : 1.0f;
        const int coloff = (x < 8) ? bn : (bn - 1024);
#pragma unroll
        for (int mt = 0; mt < 4; ++mt)
#pragma unroll
            for (int nt = 0; nt < 4; ++nt)
#pragma unroll
                for (int i = 0; i < 4; ++i) {
                    int row = bm + wm * 64 + mt * 16 + fq * 4 + i;  // (s*2+b)
                    int col = coloff + wn * 64 + nt * 16 + fr;      // 0..1023
                    int s = row >> 1, b = row & 1;
                    int h = col >> 6, dk = col & 63;
                    base[((b * 16 + h) * 2048 + s) * 64 + dk] = (f16)(acc[mt][nt][i] * scale);
                }
    } else {
        // V block: LDS transpose (2 passes over wn halves) -> vt[bh][dk][s]
        const int xb = x - 16;              // 0..7
        const int s0 = bm >> 1;             // 64-aligned s base
        f16* Ts = &As[0][0];                // [128][76] = 9728 f16 (fits in As[3][4096])
#pragma unroll
        for (int p = 0; p < 2; ++p) {
            __syncthreads();
            if (wn == p) {
#pragma unroll
                for (int mt = 0; mt < 4; ++mt)
#pragma unroll
                    for (int nt = 0; nt < 4; ++nt)
#pragma unroll
                        for (int i = 0; i < 4; ++i) {
                            int row = wm * 64 + mt * 16 + fq * 4 + i;  // 0..127 local
                            int cl = nt * 16 + fr;                     // 0..63 local col
                            Ts[(cl * 2 + (row & 1)) * 76 + (row >> 1)] = (f16)acc[mt][nt][i];
                        }
            }
            __syncthreads();
            const int h = xb * 2 + p;
            const int sj = tid & 7;
#pragma unroll
            for (int it = 0; it < 4; ++it) {
                int idx = (tid >> 3) + it * 32;     // 0..127
                int bsel = idx & 1, dk = idx >> 1;  // b, dk(=cl)
                f16x8 v = *(const f16x8*)&Ts[(dk * 2 + bsel) * 76 + sj * 8];
                *(f16x8*)&outvt[((bsel * 16 + h) * 64 + dk) * 2048 + s0 + sj * 8] = v;
            }
        }
    }
}

// ---------------- Flash attention (causal) — R20: 32x32 MFMA, in-register P ----------------
// R17 skeleton kept (512 blocks, qpair/XCD map, KVBLK=128 ring-2 pairs, vmcnt(0)+
// barrier per pair). NEW: 256-thread blocks (4 waves); each wave owns 32 q-rows via
// 32x32x16 MFMA and ONE k-parity (waves split even/odd chunks) -> still 16 waves/CU,
// same barrier count, same per-wave FLOP/iter. P never touches LDS (T12): swapped
// QK^T (mfma(K,Q)) -> lane pair {l, l+32} holds P-row for q = qrow+(l&31); 16 packs
// + 8 v_permlane32_swap_b32 assemble PV A-frags in-register. plds DELETED.
// Per wave-iter: LDS b128 ops 36+8w -> 16; MFMA-pipe 160 -> 128 cyc; no lgkm chain.
// Wave roles: isB=w<4 (tile 31-qpair vs qpair), sub=w&1 (32-row half), par=(w>>1)&1.
// Parity partials (o, lsum) combine once at end through dead K/V LDS.
// 32x32 layouts (guide-verified C/D): col=lane&31, row=(reg&3)+8(reg>>2)+4(lane>>5);
// A-frag: row=lane&31, k=(lane>>5)*8+e; B-frag: col=lane&31, k=(lane>>5)*8+e.
__global__ __launch_bounds__(256, 2) void attn_kernel(
    const f16* __restrict__ qg, const f16* __restrict__ kg,
    const f16* __restrict__ vtg, f16* __restrict__ attn)
{
    __shared__ __align__(16) char smem[65536];
    // layout: Ks = smem[0 .. 32767]  (2 bufs x 2 chunks x 4096 f16)
    //         Vs = smem[32768 .. 65535]
    // post-loop overlay: comb f32[4][32][64] @0 (32KB), comb_l f32[4][32] @32768
    f16* KsB = (f16*)smem;
    f16* VsB = (f16*)(smem + 32768);
    float* comb   = (float*)smem;
    float* comb_l = (float*)(smem + 32768);

    const int tid = threadIdx.x;
    const int lane = tid & 63;
    const int wave = tid >> 6;      // 0..3
    const int l31 = lane & 31;
    const int hi = lane >> 5;

    // XCD-aware remap (bijective on 512): XCD = w&7 == bh&7
    const int w = blockIdx.x + (blockIdx.y << 4);
    const int xcd = w & 7;
    const int idx = w >> 3;                  // 0..63 within XCD, dispatch order
    const int bh = xcd + ((idx & 3) << 3);   // 0..31, bh%8 == xcd
    const int qpair = idx >> 2;              // 0..15, longest stream first

    const int b = bh >> 4, h = bh & 15;

    const bool isB = wave < 2 || wave < 4 ? (wave < 4 && (wave >> 2) == 0) : false;
    // waves 0-3: simpler direct roles
    const int sub = wave & 1;                // 32-row half within the 64-row tile
    const int par = (wave >> 1) & 1;         // k-parity this wave computes
    const int tile = (wave < 2 || par == ((wave >> 1) & 1)) ? 0 : 0; // placeholder
    // role: waves 0,1,2,3 -> tile B (31-qpair); we need 2 tiles x 2 subs x 2 par = 8
    // with only 4 waves: tile split is across BLOCK halves? No — 4 waves cover ONE
    // 64-row tile x 2 subs x 2 parities. Block covers BOTH tiles via A/B split in
    // wave pairs? 4 waves = 1 tile. So: block handles tile B AND tile A by giving
    // waves 0-1 tile B (subs 0,1) parity = sub? That breaks parity split.
    // RESOLUTION: 4 waves cover 128 rows = both tiles WITHOUT parity split:
    // wave w: tile = (w<2)? (31-qpair) : qpair; sub = w&1; wave computes ALL chunks.
    const int mytile = (wave < 2) ? (31 - qpair) : qpair;
    const int qrow = mytile * 64 + sub * 32;
    const int nB = 32 - qpair;               // chunks staged by the block
    const int nK = mytile + 1;               // chunks this wave computes

    const f16* Q  = qg  + bh * 2048 * 64;
    const f16* K  = kg  + bh * 2048 * 64;
    const f16* VT = vtg + bh * 64 * 2048;

    const int sr2 = tid >> 3;                // 0..31
    const int scu = (tid & 7) ^ (sr2 & 7);

    // Q fragments (B-operand of swapped QK^T): lane holds Q[q=qrow+l31][d=t*16+hi*8+e]
    f16x8 aq[4];
#pragma unroll
    for (int t = 0; t < 4; ++t)
        aq[t] = *(const f16x8*)&Q[(qrow + l31) * 64 + t * 16 + hi * 8];

    f32x16 o0 = {}, o1 = {};
    float lsum = 0.f;
    const int qmax = qrow + l31;             // this lane's q (for masking)

    // stage one 64-chunk (kc) into half hh of pair-buffer buf (4 gloads, 256 thr)
    auto stage64 = [&](int kc, int buf, int hh) {
        const int kb = kc * 64;
        f16* kd = KsB + buf * 8192 + hh * 4096;
        f16* vd = VsB + buf * 8192 + hh * 4096;
        gload_lds16(&K[(kb + sr2) * 64 + scu * 8],          &kd[tid * 8]);
        gload_lds16(&K[(kb + sr2 + 32) * 64 + scu * 8],     &kd[2048 + tid * 8]);
        gload_lds16(&VT[sr2 * 2048 + kb + scu * 8],         &vd[tid * 8]);
        gload_lds16(&VT[(sr2 + 32) * 2048 + kb + scu * 8],  &vd[2048 + tid * 8]);
    };

    auto compute32 = [&](int kb, const f16* Ksb, const f16* Vsb, bool domask) {
        f32x16 sc0 = {}, sc1 = {};
        // swapped QK^T: two 32-k S^T tiles; A=K rows, B=Q^T. Lane's q = qrow+l31.
        __builtin_amdgcn_s_setprio(1);
#pragma unroll
        for (int t = 0; t < 4; ++t) {
            f16x8 kf0 = *(const f16x8*)&Ksb[l31 * 64 + (((2 * t + hi) ^ (l31 & 7)) * 8)];
            f16x8 kf1 = *(const f16x8*)&Ksb[(32 + l31) * 64 + (((2 * t + hi) ^ (l31 & 7)) * 8)];
            sc0 = MFMA32(kf0, aq[t], sc0);
            sc1 = MFMA32(kf1, aq[t], sc1);
        }
        __builtin_amdgcn_s_setprio(0);
        // mask + exp2; k_local(r) = (r&3) + 8*(r>>2) + 4*hi
        float p0[16], p1[16];
#pragma unroll
        for (int r = 0; r < 16; ++r) {
            const int kl = (r & 3) + 8 * (r >> 2) + 4 * hi;
            float s0 = sc0[r], s1 = sc1[r];
            if (domask) {
                if (kb + kl > qmax)      s0 = -1e30f;
                if (kb + 32 + kl > qmax) s1 = -1e30f;
            }
            float e0 = __builtin_amdgcn_exp2f(s0);
            float e1 = __builtin_amdgcn_exp2f(s1);
            p0[r] = e0; p1[r] = e1;
            lsum += e0 + e1;
        }
        // P -> PV A-frags in-register: per ks, pack 4 words + 2 permlane swaps.
        // apk[ks][e] = P[q][ks*16 + hi*8 + e]; post-swap a_j = low-e, b_j = high-e.
#pragma unroll
        for (int ks = 0; ks < 4; ++ks) {
            const int rb = 8 * (ks & 1);
            const float* pp = (ks < 2) ? p0 : p1;
            unsigned a0 = pack2(pp[rb + 0], pp[rb + 1]);
            unsigned a1 = pack2(pp[rb + 2], pp[rb + 3]);
            unsigned b0 = pack2(pp[rb + 4], pp[rb + 5]);
            unsigned b1 = pack2(pp[rb + 6], pp[rb + 7]);
            asm("v_permlane32_swap_b32 %0, %1" : "+v"(a0), "+v"(b0));
            asm("v_permlane32_swap_b32 %0, %1" : "+v"(a1), "+v"(b1));
            uint4 W = {a0, a1, b0, b1};
            f16x8 apk = __builtin_bit_cast(f16x8, W);
            f16x8 vf0 = *(const f16x8*)&Vsb[l31 * 64 + (((2 * ks + hi) ^ (l31 & 7)) * 8)];
            f16x8 vf1 = *(const f16x8*)&Vsb[(32 + l31) * 64 + (((2 * ks + hi) ^ (l31 & 7)) * 8)];
            __builtin_amdgcn_s_setprio(1);
            o0 = MFMA32(apk, vf0, o0);
            o1 = MFMA32(apk, vf1, o1);
            __builtin_amdgcn_s_setprio(0);
        }
    };

    // prologue: stage pair 0 (chunks 0,1 — nB>=17 so both exist), drain, barrier
    stage64(0, 0, 0);
    stage64(1, 0, 1);
    asm volatile("s_waitcnt vmcnt(0)" ::: "memory");
    __builtin_amdgcn_s_barrier();
    __builtin_amdgcn_sched_barrier(0);

    const int nP = (nB + 1) >> 1;            // pair count (9..16)
#pragma unroll 1
    for (int ip = 0; ip < nP; ++ip) {
        const int buf = ip & 1;
        if (ip + 1 < nP) {
            stage64(2 * ip + 2, buf ^ 1, 0);
            if (2 * ip + 3 < nB) stage64(2 * ip + 3, buf ^ 1, 1);
        }
        const int kc0 = 2 * ip, kc1 = 2 * ip + 1;
        const f16* Kb = KsB + buf * 8192;
        const f16* Vb = VsB + buf * 8192;
        if (kc0 < nK) compute32(kc0 * 64, Kb, Vb, kc0 * 64 + 63 > qrow);
        if (kc1 < nK) compute32(kc1 * 64, Kb + 4096, Vb + 4096, kc1 * 64 + 63 > qrow);
        asm volatile("s_waitcnt vmcnt(0)" ::: "memory");
        __builtin_amdgcn_s_barrier();
        __builtin_amdgcn_sched_barrier(0);
        if (false) (void)0;
    }

    // epilogue: lane-pair {l, l+32} share q -> full row-sum via xor-32 shuffle.
    float rs = lsum + __shfl_xor(lsum, 32);
    float inv = __builtin_amdgcn_rcpf(rs);
    // Output: o regs hold O[q = qrow + rq(r)][dk = nt*32 + l31],
    // rq(r) = (r&3)+8*(r>>2)+4*hi. inv lives at lane (q&31) -> shfl broadcast.
#pragma unroll
    for (int r = 0; r < 16; ++r) {
        const int rq = (r & 3) + 8 * (r >> 2) + 4 * hi;
        float invr = __shfl(inv, rq);
        const int srow = qrow + rq;
        attn[(srow * 2 + b) * 1024 + h * 64 + l31]      = (f16)(o0[r] * invr);
        attn[(srow * 2 + b) * 1024 + h * 64 + 32 + l31] = (f16)(o1[r] * invr);
    }
    (void)comb; (void)comb_l;   // parity-combine path unused in 4-wave/no-split form
}

// ---------------- Out GEMM: out[4096x1024] = A[4096x1024] * Wout^T + bias ----------------
// R19 structure kept: R7 ring-3 BK=32 + XCD-aware 2D-chunked remap.
__global__ __launch_bounds__(256) void gemm_out(
    const f16* __restrict__ A, const f16* __restrict__ B,
    const float* __restrict__ bias, float* __restrict__ out)
{
    __shared__ f16 As[3][128 * 32];
    __shared__ f16 Bs[3][64 * 32];
    const int tid = threadIdx.x;
    const int lane = tid & 63;
    const int wave = tid >> 6;
    const int wm = wave >> 1, wn = wave & 1;

    const int wlin = blockIdx.x + 16 * blockIdx.y;
    const int xcd = wlin & 7;
    const int ii = wlin >> 3;                   // 0..63
    const int bxx = 8 * (xcd & 1) + (ii & 7);   // 0..15
    const int byy = 8 * (xcd >> 1) + (ii >> 3); // 0..31

    const int bm = byy * 128, bn = bxx * 64;
    const int fr = lane & 15, fq = lane >> 4;

    const int srow = tid >> 2;                                    // 0..63
    const int su = (tid & 3) ^ (srow & 3) ^ ((srow >> 2) & 3);
    const int uoff = (fq ^ (fr & 3) ^ ((fr >> 2) & 3)) * 8;

    f32x4 acc[4][2] = {};

    auto stg = [&](int tt, int buf) {
        const int k0 = tt * 32;
        gload_lds16(&A[(bm + srow) * 1024 + k0 + su * 8],      &As[buf][tid * 8]);
        gload_lds16(&A[(bm + 64 + srow) * 1024 + k0 + su * 8], &As[buf][2048 + tid * 8]);
        gload_lds16(&B[(bn + srow) * 1024 + k0 + su * 8],      &Bs[buf][tid * 8]);
    };

    auto step = [&](int t, int buf) {
        const int b2 = (buf + 2 >= 3) ? (buf - 1) : (buf + 2);
        if (t < 30) stg(t + 2, b2);
        f16x8 af[4], bf[2];
#pragma unroll
        for (int mt = 0; mt < 4; ++mt)
            af[mt] = *(const f16x8*)&As[buf][(wm * 64 + mt * 16 + fr) * 32 + uoff];
#pragma unroll
        for (int nt = 0; nt < 2; ++nt)
            bf[nt] = *(const f16x8*)&Bs[buf][(wn * 32 + nt * 16 + fr) * 32 + uoff];
        __builtin_amdgcn_s_setprio(1);
#pragma unroll
        for (int mt = 0; mt < 4; ++mt)
#pragma unroll
            for (int nt = 0; nt < 2; ++nt)
                acc[mt][nt] = MFMA16(af[mt], bf[nt], acc[mt][nt]);
        __builtin_amdgcn_s_setprio(0);
        if (t < 30) { asm volatile("s_waitcnt vmcnt(3)" ::: "memory"); }
        else        { asm volatile("s_waitcnt vmcnt(0)" ::: "memory"); }
        __builtin_amdgcn_s_barrier();
        __builtin_amdgcn_sched_barrier(0);
    };

    stg(0, 0);
    stg(1, 1);
    asm volatile("s_waitcnt vmcnt(3)" ::: "memory");
    __builtin_amdgcn_s_barrier();
    __builtin_amdgcn_sched_barrier(0);
#pragma unroll 1
    for (int tb = 0; tb < 30; tb += 3) {
        step(tb, 0);
        step(tb + 1, 1);
        step(tb + 2, 2);
    }
    step(30, 0);
    step(31, 1);

#pragma unroll
    for (int mt = 0; mt < 4; ++mt)
#pragma unroll
        for (int nt = 0; nt < 2; ++nt)
#pragma unroll
            for (int i = 0; i < 4; ++i) {
                int row = bm + wm * 64 + mt * 16 + fq * 4 + i;
                int col = bn + wn * 32 + nt * 16 + fr;
                out[row * 1024 + col] = acc[mt][nt][i] + bias[col];
            }
}

extern "C" void kernel_launch(void* const* d_in, const int* in_sizes, int n_in,
                              void* d_out, int out_size, void* d_ws, size_t ws_size,
                              hipStream_t stream)
{
    const float* x     = (const float*)d_in[0];
    const float* w_qkv = (const float*)d_in[1];
    const float* w_out = (const float*)d_in[2];
    const float* b_out = (const float*)d_in[3];
    float* out = (float*)d_out;

    char* ws = (char*)d_ws;
    f16* xh  = (f16*)(ws);
    f16* wqh = (f16*)(ws + 8388608);
    f16* woh = (f16*)(ws + 14680064);
    f16* qh  = (f16*)(ws + 16777216);
    f16* kh  = (f16*)(ws + 25165824);
    f16* vt  = (f16*)(ws + 33554432);
    f16* ah  = (f16*)(ws + 41943040);

    cast_all<<<8192, 256, 0, stream>>>(x, w_qkv, w_out, xh);
    gemm_qkv<<<dim3(24, 32), 256, 0, stream>>>(xh, wqh, qh, kh, vt);
    attn_kernel<<<dim3(16, 32), 256, 0, stream>>>(qh, kh, vt, ah);
    gemm_out<<<dim3(16, 32), 256, 0, stream>>>(ah, woh, b_out, out);
}